// Round 8
// baseline (362.491 us; speedup 1.0000x reference)
//
#include <hip/hip_runtime.h>
#include <hip/hip_bf16.h>

// GRU policy: B=2048, T=512, V=4, E=64, H=128.
// R7 = R6 + sched_barrier(0) fences pinning MFMA/trans interleave.
// Model from R6: per-SIMD-step = 466 cyc MFMA issue + ~740 cyc VALU issue,
// ~zero overlap because LLVM clusters all MFMAs then all gate VALU (this is
// why R4's source-level antiphase was neutral). Fences force each wave's
// stream to alternate [MFMA group]/[trans group] so the matrix pipe fills
// under the trans/VALU issue of the same + partner wave.
// Per wave/step: 12 MFMA, 7 ds_read_b128 + 1 ds_read_u8 + 1 ds_write_b64,
// 24 trans. 1 barrier/step. 128 blocks (structural: MFMA M=16, B/16).

#define B_  2048
#define T_  512
#define V_  4
#define E_  64
#define H_  128
#define G3  384
#define SH  136            // h row stride (bf16 elems)

#define LOG2E 1.4426950408889634f

typedef __attribute__((ext_vector_type(8))) short  short8;   // 8 bf16
typedef __attribute__((ext_vector_type(4))) float  float4v;
typedef unsigned long long ull;

__device__ __forceinline__ short bf16s(float f) {            // RNE scalar (setup only)
  union { float ff; unsigned int u; } c; c.ff = f;
  return (short)((c.u + 0x7fffu + ((c.u >> 16) & 1u)) >> 16);
}

// table[v][g] = scale_g * (b_ih[g] + sum_e W_ih[g,e]*emb[v,e] (+ b_hh[g] for g<2H))
// scale_g = -log2e for r,z rows; +2*log2e for n rows (b_hh_n NOT folded).
__global__ void gi_table_kernel(const float* __restrict__ emb,
                                const float* __restrict__ W_ih,
                                const float* __restrict__ b_ih,
                                const float* __restrict__ b_hh,
                                float* __restrict__ table) {
  int gid = blockIdx.x * blockDim.x + threadIdx.x;
  if (gid >= V_ * G3) return;
  int v = gid / G3;
  int g = gid - v * G3;
  float acc = b_ih[g];
  if (g < 2 * H_) acc += b_hh[g];
  const float* wr = W_ih + g * E_;
  const float* er = emb + v * E_;
#pragma unroll 8
  for (int e = 0; e < E_; ++e) acc += wr[e] * er[e];
  table[gid] = acc * ((g < 2 * H_) ? -LOG2E : 2.f * LOG2E);
}

#define MFMA16(A, B, C) __builtin_amdgcn_mfma_f32_16x16x32_bf16((A), (B), (C), 0, 0, 0)
#define SFENCE() __builtin_amdgcn_sched_barrier(0)

__global__ __launch_bounds__(512) void gru_kernel(
    const int* __restrict__ x, const float* __restrict__ W_hh,
    const float* __restrict__ b_hh, const float* __restrict__ W_fc,
    const float* __restrict__ b_fc, const float* __restrict__ table,
    float* __restrict__ out) {
  __shared__ __align__(16) short hbuf[2][16 * SH];          // bf16 h, double-buffered
  __shared__ __align__(16) unsigned char xs[(T_ + 2) * 16]; // tokens [t][row], 2 pad rows
  __shared__ __align__(16) float tabS[V_ * G3];             // gi table (pre-scaled)
  __shared__ __align__(16) float hf[16 * H_];               // epilogue fp32 h

  const int tid  = threadIdx.x;
  const int w    = tid >> 6;        // wave 0..7
  const int lane = tid & 63;
  const int m    = lane & 15;       // batch row (B/C col) and A gate-row
  const int q    = lane >> 4;       // quad
  const int g0   = blockIdx.x * 16;

  // ---- stage x -> xs[t][r] bytes; zero the 2 pad rows ----
  for (int i = tid; i < 16 * T_; i += 512) {
    int r = i >> 9;                 // 0..15
    int t = i & (T_ - 1);
    xs[t * 16 + r] = (unsigned char)(x[(g0 + r) * T_ + t] & 3);
  }
  if (tid < 32) xs[T_ * 16 + tid] = 0;
  // ---- stage gi table to LDS ----
  for (int i = tid; i < V_ * G3; i += 512) tabS[i] = table[i];
  // ---- h0 = 0 ----
  for (int i = tid; i < 16 * SH; i += 512) hbuf[0][i] = 0;

  // ---- persistent A-fragments: W_hh tiles (pre-scaled), A[g=m][k=q*8+j] ----
  short8 wA[3][4];
#pragma unroll
  for (int s = 0; s < 3; ++s) {
    const float sc = (s < 2) ? -LOG2E : 2.f * LOG2E;
    const float* wrow = W_hh + (s * H_ + w * 16 + m) * H_;
#pragma unroll
    for (int ks = 0; ks < 4; ++ks) {
      const float* p = wrow + ks * 32 + q * 8;
      short8 f;
#pragma unroll
      for (int jj = 0; jj < 8; ++jj) f[jj] = bf16s(p[jj] * sc);
      wA[s][ks] = f;
    }
  }

  const int c0 = w * 16 + q * 4;    // this lane's h-col base
  float4v bhnC;                     // a2 chain C-init: b_hh_n * 2log2e
  {
    const float* p = b_hh + 2 * H_ + c0;
#pragma unroll
    for (int i = 0; i < 4; ++i) bhnC[i] = p[i] * 2.f * LOG2E;
  }
  float h_old[4] = {0.f, 0.f, 0.f, 0.f};

  __syncthreads();

  // ---- prologue: gi(0) + token byte of t=1 ----
  float4v giR, giZ, giN;
  int vb1;
  {
    int v0 = xs[m] & 3;
    const float* tb = &tabS[v0 * G3 + c0];
    giR = *(const float4v*)(tb);
    giZ = *(const float4v*)(tb + H_);
    giN = *(const float4v*)(tb + 2 * H_);
    vb1 = xs[16 + m];
  }

  auto step = [&](int FROM, int TO, int t) {
    // h fragments + next-step gi preloads (LDS pipe; before the first fence)
    const short* rbp = &hbuf[FROM][m * SH + q * 8];
    short8 h0 = *(const short8*)(rbp);
    short8 h1 = *(const short8*)(rbp + 32);
    short8 h2 = *(const short8*)(rbp + 64);
    short8 h3 = *(const short8*)(rbp + 96);
    int vb2 = xs[(t + 2) * 16 + m];
    const float* tbn = &tabS[(vb1 & 3) * G3 + c0];
    float4v giRn = *(const float4v*)(tbn);
    float4v giZn = *(const float4v*)(tbn + H_);
    float4v giNn = *(const float4v*)(tbn + 2 * H_);

    // ---- group 1: a0 chain + first half of a2 ----
    float4v a0 = MFMA16(wA[0][0], h0, giR);
    a0 = MFMA16(wA[0][1], h1, a0);
    a0 = MFMA16(wA[0][2], h2, a0);
    a0 = MFMA16(wA[0][3], h3, a0);
    float4v a2 = MFMA16(wA[2][0], h0, bhnC);
    a2 = MFMA16(wA[2][1], h1, a2);
    SFENCE();
    // ---- group 2: r sigmoid (trans pipe fills while a2 queue drains) ----
    float r0 = __builtin_amdgcn_rcpf(1.f + __builtin_amdgcn_exp2f(a0[0]));
    float r1 = __builtin_amdgcn_rcpf(1.f + __builtin_amdgcn_exp2f(a0[1]));
    float r2 = __builtin_amdgcn_rcpf(1.f + __builtin_amdgcn_exp2f(a0[2]));
    float r3 = __builtin_amdgcn_rcpf(1.f + __builtin_amdgcn_exp2f(a0[3]));
    SFENCE();
    // ---- group 3: rest of a2 + first half of a1 ----
    a2 = MFMA16(wA[2][2], h2, a2);
    a2 = MFMA16(wA[2][3], h3, a2);
    float4v a1 = MFMA16(wA[1][0], h0, giZ);
    a1 = MFMA16(wA[1][1], h1, a1);
    SFENCE();
    // ---- group 4: np / tanh ----
    float nn[4];
    {
      float np0 = __fmaf_rn(r0, a2[0], giN[0]);
      float np1 = __fmaf_rn(r1, a2[1], giN[1]);
      float np2 = __fmaf_rn(r2, a2[2], giN[2]);
      float np3 = __fmaf_rn(r3, a2[3], giN[3]);
      nn[0] = __fmaf_rn(-2.f, __builtin_amdgcn_rcpf(__builtin_amdgcn_exp2f(np0) + 1.f), 1.f);
      nn[1] = __fmaf_rn(-2.f, __builtin_amdgcn_rcpf(__builtin_amdgcn_exp2f(np1) + 1.f), 1.f);
      nn[2] = __fmaf_rn(-2.f, __builtin_amdgcn_rcpf(__builtin_amdgcn_exp2f(np2) + 1.f), 1.f);
      nn[3] = __fmaf_rn(-2.f, __builtin_amdgcn_rcpf(__builtin_amdgcn_exp2f(np3) + 1.f), 1.f);
    }
    SFENCE();
    // ---- group 5: tail of a1 ----
    a1 = MFMA16(wA[1][2], h2, a1);
    a1 = MFMA16(wA[1][3], h3, a1);
    SFENCE();
    // ---- group 6: z, blend, pack, write ----
    unsigned int rb_[4];
#pragma unroll
    for (int i = 0; i < 4; ++i) {
      float z  = __builtin_amdgcn_rcpf(1.f + __builtin_amdgcn_exp2f(a1[i]));
      float hn = __fmaf_rn(z, h_old[i] - nn[i], nn[i]);
      h_old[i] = hn;
      union { float ff; unsigned int u; } c; c.ff = hn;
      rb_[i] = c.u + 0x8000u;                        // round-half-up to bf16
    }
    unsigned int pk0 = __builtin_amdgcn_perm(rb_[1], rb_[0], 0x07060302u);
    unsigned int pk1 = __builtin_amdgcn_perm(rb_[3], rb_[2], 0x07060302u);
    *(ull*)(&hbuf[TO][m * SH + c0]) = ((ull)pk1 << 32) | pk0;
    // rotate preloads
    giR = giRn; giZ = giZn; giN = giNn; vb1 = vb2;
    __syncthreads();
  };

  for (int t = 0; t < T_; t += 2) {
    step(0, 1, t);
    step(1, 0, t + 1);
  }

  // ---- epilogue: logits = hT @ W_fc^T + b_fc ----
  float4v hv;
#pragma unroll
  for (int i = 0; i < 4; ++i) hv[i] = h_old[i];
  *(float4v*)(&hf[m * H_ + c0]) = hv;
  __syncthreads();

  if (tid < 64) {
    int row = tid >> 2, vo = tid & 3;
    float s = b_fc[vo];
    const float* wv = W_fc + vo * H_;
    const float* hr = &hf[row * H_];
#pragma unroll 4
    for (int k = 0; k < H_; k += 4)
      s += hr[k] * wv[k] + hr[k + 1] * wv[k + 1]
         + hr[k + 2] * wv[k + 2] + hr[k + 3] * wv[k + 3];
    out[(g0 + row) * V_ + vo] = s;
  }
}

extern "C" void kernel_launch(void* const* d_in, const int* in_sizes, int n_in,
                              void* d_out, int out_size, void* d_ws, size_t ws_size,
                              hipStream_t stream) {
  const int*   x    = (const int*)d_in[0];
  const float* emb  = (const float*)d_in[1];
  const float* W_ih = (const float*)d_in[2];
  const float* W_hh = (const float*)d_in[3];
  const float* b_ih = (const float*)d_in[4];
  const float* b_hh = (const float*)d_in[5];
  const float* W_fc = (const float*)d_in[6];
  const float* b_fc = (const float*)d_in[7];
  float* out   = (float*)d_out;
  float* table = (float*)d_ws;     // 4*384 fp32 = 6 KB

  gi_table_kernel<<<(V_ * G3 + 255) / 256, 256, 0, stream>>>(emb, W_ih, b_ih, b_hh, table);
  gru_kernel<<<B_ / 16, 512, 0, stream>>>(x, W_hh, b_hh, W_fc, b_fc, table, out);
}

// Round 9
// 341.214 us; speedup vs baseline: 1.0624x; 1.0624x over previous
//
#include <hip/hip_runtime.h>
#include <hip/hip_bf16.h>

// GRU policy: B=2048, T=512, V=4, E=64, H=128.
// R8 = R6 with the step body re-sequenced (R7 fences reverted — regression):
//  (1) ALL 12 MFMAs issued first (a1/z chain leads, a0/r, then a2/n) so the
//      first MFMA waits only on the 4 h ds_reads (in-order DS completion),
//      not on next-step gi preloads.
//  (2) z/r sigmoids right after the MFMA block -> execute under queue drain.
//  (3) gi preloads + token byte moved to the TAIL (consumed next step; hide
//      behind blend/pack/barrier instead of gating this step's MFMAs).
//  (4) tail = np/tanh/blend/pack only.
// Per wave/step: 12 MFMA, 7 ds_read_b128 + 1 ds_read_u8 + 1 ds_write_b64,
// 24 trans. 1 barrier/step. 128 blocks (structural: MFMA M=16, B/16).

#define B_  2048
#define T_  512
#define V_  4
#define E_  64
#define H_  128
#define G3  384
#define SH  136            // h row stride (bf16 elems)

#define LOG2E 1.4426950408889634f

typedef __attribute__((ext_vector_type(8))) short  short8;   // 8 bf16
typedef __attribute__((ext_vector_type(4))) float  float4v;
typedef unsigned long long ull;

__device__ __forceinline__ short bf16s(float f) {            // RNE scalar (setup only)
  union { float ff; unsigned int u; } c; c.ff = f;
  return (short)((c.u + 0x7fffu + ((c.u >> 16) & 1u)) >> 16);
}

// table[v][g] = scale_g * (b_ih[g] + sum_e W_ih[g,e]*emb[v,e] (+ b_hh[g] for g<2H))
// scale_g = -log2e for r,z rows; +2*log2e for n rows (b_hh_n NOT folded).
__global__ void gi_table_kernel(const float* __restrict__ emb,
                                const float* __restrict__ W_ih,
                                const float* __restrict__ b_ih,
                                const float* __restrict__ b_hh,
                                float* __restrict__ table) {
  int gid = blockIdx.x * blockDim.x + threadIdx.x;
  if (gid >= V_ * G3) return;
  int v = gid / G3;
  int g = gid - v * G3;
  float acc = b_ih[g];
  if (g < 2 * H_) acc += b_hh[g];
  const float* wr = W_ih + g * E_;
  const float* er = emb + v * E_;
#pragma unroll 8
  for (int e = 0; e < E_; ++e) acc += wr[e] * er[e];
  table[gid] = acc * ((g < 2 * H_) ? -LOG2E : 2.f * LOG2E);
}

#define MFMA16(A, B, C) __builtin_amdgcn_mfma_f32_16x16x32_bf16((A), (B), (C), 0, 0, 0)

__global__ __launch_bounds__(512) void gru_kernel(
    const int* __restrict__ x, const float* __restrict__ W_hh,
    const float* __restrict__ b_hh, const float* __restrict__ W_fc,
    const float* __restrict__ b_fc, const float* __restrict__ table,
    float* __restrict__ out) {
  __shared__ __align__(16) short hbuf[2][16 * SH];          // bf16 h, double-buffered
  __shared__ __align__(16) unsigned char xs[(T_ + 2) * 16]; // tokens [t][row], 2 pad rows
  __shared__ __align__(16) float tabS[V_ * G3];             // gi table (pre-scaled)
  __shared__ __align__(16) float hf[16 * H_];               // epilogue fp32 h

  const int tid  = threadIdx.x;
  const int w    = tid >> 6;        // wave 0..7
  const int lane = tid & 63;
  const int m    = lane & 15;       // batch row (B/C col) and A gate-row
  const int q    = lane >> 4;       // quad
  const int g0   = blockIdx.x * 16;

  // ---- stage x -> xs[t][r] bytes; zero the 2 pad rows ----
  for (int i = tid; i < 16 * T_; i += 512) {
    int r = i >> 9;                 // 0..15
    int t = i & (T_ - 1);
    xs[t * 16 + r] = (unsigned char)(x[(g0 + r) * T_ + t] & 3);
  }
  if (tid < 32) xs[T_ * 16 + tid] = 0;
  // ---- stage gi table to LDS ----
  for (int i = tid; i < V_ * G3; i += 512) tabS[i] = table[i];
  // ---- h0 = 0 ----
  for (int i = tid; i < 16 * SH; i += 512) hbuf[0][i] = 0;

  // ---- persistent A-fragments: W_hh tiles (pre-scaled), A[g=m][k=q*8+j] ----
  short8 wA[3][4];
#pragma unroll
  for (int s = 0; s < 3; ++s) {
    const float sc = (s < 2) ? -LOG2E : 2.f * LOG2E;
    const float* wrow = W_hh + (s * H_ + w * 16 + m) * H_;
#pragma unroll
    for (int ks = 0; ks < 4; ++ks) {
      const float* p = wrow + ks * 32 + q * 8;
      short8 f;
#pragma unroll
      for (int jj = 0; jj < 8; ++jj) f[jj] = bf16s(p[jj] * sc);
      wA[s][ks] = f;
    }
  }

  const int c0 = w * 16 + q * 4;    // this lane's h-col base
  float4v bhnC;                     // a2 chain C-init: b_hh_n * 2log2e
  {
    const float* p = b_hh + 2 * H_ + c0;
#pragma unroll
    for (int i = 0; i < 4; ++i) bhnC[i] = p[i] * 2.f * LOG2E;
  }
  float h_old[4] = {0.f, 0.f, 0.f, 0.f};

  __syncthreads();

  // ---- prologue: gi(0) + token byte of t=1 ----
  float4v giR, giZ, giN;
  int vb1;
  {
    int v0 = xs[m] & 3;
    const float* tb = &tabS[v0 * G3 + c0];
    giR = *(const float4v*)(tb);
    giZ = *(const float4v*)(tb + H_);
    giN = *(const float4v*)(tb + 2 * H_);
    vb1 = xs[16 + m];
  }

  auto step = [&](int FROM, int TO, int t) {
    // h fragments — the ONLY LDS reads that gate this step's MFMAs
    const short* rbp = &hbuf[FROM][m * SH + q * 8];
    short8 h0 = *(const short8*)(rbp);
    short8 h1 = *(const short8*)(rbp + 32);
    short8 h2 = *(const short8*)(rbp + 64);
    short8 h3 = *(const short8*)(rbp + 96);

    // ---- all 12 MFMAs up front; z-chain (a1) leads, a2 last ----
    float4v a1 = MFMA16(wA[1][0], h0, giZ);
    a1 = MFMA16(wA[1][1], h1, a1);
    a1 = MFMA16(wA[1][2], h2, a1);
    a1 = MFMA16(wA[1][3], h3, a1);
    float4v a0 = MFMA16(wA[0][0], h0, giR);
    a0 = MFMA16(wA[0][1], h1, a0);
    a0 = MFMA16(wA[0][2], h2, a0);
    a0 = MFMA16(wA[0][3], h3, a0);
    float4v a2 = MFMA16(wA[2][0], h0, bhnC);
    a2 = MFMA16(wA[2][1], h1, a2);
    a2 = MFMA16(wA[2][2], h2, a2);
    a2 = MFMA16(wA[2][3], h3, a2);

    // ---- z then r sigmoids: execute under the MFMA queue drain ----
    float z0 = __builtin_amdgcn_rcpf(1.f + __builtin_amdgcn_exp2f(a1[0]));
    float z1 = __builtin_amdgcn_rcpf(1.f + __builtin_amdgcn_exp2f(a1[1]));
    float z2 = __builtin_amdgcn_rcpf(1.f + __builtin_amdgcn_exp2f(a1[2]));
    float z3 = __builtin_amdgcn_rcpf(1.f + __builtin_amdgcn_exp2f(a1[3]));
    float r0 = __builtin_amdgcn_rcpf(1.f + __builtin_amdgcn_exp2f(a0[0]));
    float r1 = __builtin_amdgcn_rcpf(1.f + __builtin_amdgcn_exp2f(a0[1]));
    float r2 = __builtin_amdgcn_rcpf(1.f + __builtin_amdgcn_exp2f(a0[2]));
    float r3 = __builtin_amdgcn_rcpf(1.f + __builtin_amdgcn_exp2f(a0[3]));

    // ---- next-step gi preloads (consumed after the barrier; latency hides
    //      behind the tail + barrier, and no MFMA waits on them) ----
    int vb2 = xs[(t + 2) * 16 + m];
    const float* tbn = &tabS[(vb1 & 3) * G3 + c0];
    float4v giRn = *(const float4v*)(tbn);
    float4v giZn = *(const float4v*)(tbn + H_);
    float4v giNn = *(const float4v*)(tbn + 2 * H_);

    // ---- tail: np / tanh / blend / pack / write ----
    float np0 = __fmaf_rn(r0, a2[0], giN[0]);
    float np1 = __fmaf_rn(r1, a2[1], giN[1]);
    float np2 = __fmaf_rn(r2, a2[2], giN[2]);
    float np3 = __fmaf_rn(r3, a2[3], giN[3]);
    float nn0 = __fmaf_rn(-2.f, __builtin_amdgcn_rcpf(__builtin_amdgcn_exp2f(np0) + 1.f), 1.f);
    float nn1 = __fmaf_rn(-2.f, __builtin_amdgcn_rcpf(__builtin_amdgcn_exp2f(np1) + 1.f), 1.f);
    float nn2 = __fmaf_rn(-2.f, __builtin_amdgcn_rcpf(__builtin_amdgcn_exp2f(np2) + 1.f), 1.f);
    float nn3 = __fmaf_rn(-2.f, __builtin_amdgcn_rcpf(__builtin_amdgcn_exp2f(np3) + 1.f), 1.f);
    float hn0 = __fmaf_rn(z0, h_old[0] - nn0, nn0);
    float hn1 = __fmaf_rn(z1, h_old[1] - nn1, nn1);
    float hn2 = __fmaf_rn(z2, h_old[2] - nn2, nn2);
    float hn3 = __fmaf_rn(z3, h_old[3] - nn3, nn3);
    h_old[0] = hn0; h_old[1] = hn1; h_old[2] = hn2; h_old[3] = hn3;
    union { float ff; unsigned int u; } c0u, c1u, c2u, c3u;
    c0u.ff = hn0; c1u.ff = hn1; c2u.ff = hn2; c3u.ff = hn3;
    unsigned int pk0 = __builtin_amdgcn_perm(c1u.u + 0x8000u, c0u.u + 0x8000u, 0x07060302u);
    unsigned int pk1 = __builtin_amdgcn_perm(c3u.u + 0x8000u, c2u.u + 0x8000u, 0x07060302u);
    *(ull*)(&hbuf[TO][m * SH + c0]) = ((ull)pk1 << 32) | pk0;
    // rotate preloads
    giR = giRn; giZ = giZn; giN = giNn; vb1 = vb2;
    __syncthreads();
  };

  for (int t = 0; t < T_; t += 2) {
    step(0, 1, t);
    step(1, 0, t + 1);
  }

  // ---- epilogue: logits = hT @ W_fc^T + b_fc ----
  float4v hv;
#pragma unroll
  for (int i = 0; i < 4; ++i) hv[i] = h_old[i];
  *(float4v*)(&hf[m * H_ + c0]) = hv;
  __syncthreads();

  if (tid < 64) {
    int row = tid >> 2, vo = tid & 3;
    float s = b_fc[vo];
    const float* wv = W_fc + vo * H_;
    const float* hr = &hf[row * H_];
#pragma unroll 4
    for (int k = 0; k < H_; k += 4)
      s += hr[k] * wv[k] + hr[k + 1] * wv[k + 1]
         + hr[k + 2] * wv[k + 2] + hr[k + 3] * wv[k + 3];
    out[(g0 + row) * V_ + vo] = s;
  }
}

extern "C" void kernel_launch(void* const* d_in, const int* in_sizes, int n_in,
                              void* d_out, int out_size, void* d_ws, size_t ws_size,
                              hipStream_t stream) {
  const int*   x    = (const int*)d_in[0];
  const float* emb  = (const float*)d_in[1];
  const float* W_ih = (const float*)d_in[2];
  const float* W_hh = (const float*)d_in[3];
  const float* b_ih = (const float*)d_in[4];
  const float* b_hh = (const float*)d_in[5];
  const float* W_fc = (const float*)d_in[6];
  const float* b_fc = (const float*)d_in[7];
  float* out   = (float*)d_out;
  float* table = (float*)d_ws;     // 4*384 fp32 = 6 KB

  gi_table_kernel<<<(V_ * G3 + 255) / 256, 256, 0, stream>>>(emb, W_ih, b_ih, b_hh, table);
  gru_kernel<<<B_ / 16, 512, 0, stream>>>(x, W_hh, b_hh, W_fc, b_fc, table, out);
}